// Round 8
// baseline (167.793 us; speedup 1.0000x reference)
//
#include <hip/hip_runtime.h>
#include <hip/hip_bf16.h>

#define CCH 256
#define NSEQ 2048
#define BATCH 8

typedef __hip_bfloat16 bf16;
typedef short s8v __attribute__((ext_vector_type(8)));    // 8 bf16 (A/B frag)
typedef float f4v __attribute__((ext_vector_type(4)));    // 16x16 C/D frag
typedef float f16v __attribute__((ext_vector_type(16)));  // 32x32 C/D frag

struct __align__(8) bf16x4 { bf16 v[4]; };

__device__ __forceinline__ float b2f(bf16 h) { return __bfloat162float(h); }
__device__ __forceinline__ bf16 f2b(float f) { return __float2bfloat16(f); }

#define MFMA16(a, b, c) __builtin_amdgcn_mfma_f32_16x16x32_bf16((a), (b), (c), 0, 0, 0)
#define MFMA32(a, b, c) __builtin_amdgcn_mfma_f32_32x32x16_bf16((a), (b), (c), 0, 0, 0)

// async global->LDS 16B per lane: lds dest = uniform base + lane*16
__device__ __forceinline__ void gload_lds16(const bf16* g, bf16* l) {
    __builtin_amdgcn_global_load_lds(
        (const __attribute__((address_space(1))) unsigned int*)(g),
        (__attribute__((address_space(3))) unsigned int*)(l), 16, 0, 0);
}

// ---------------------------------------------------------------------------
// prepw: cast Wq,Wk,Wv,Wo fp32 -> bf16 once. Wq/Wk/Wv PRE-SWIZZLED
// (elem ^= (row&7)<<3) for qkvprep's LDS-DMA + swizzled ds_read_b128.
// Wo plain bf16 (outproj reads per-wave frags directly from global).
// ---------------------------------------------------------------------------
__global__ __launch_bounds__(256) void prepw_kernel(
    const float* __restrict__ wq, const float* __restrict__ wk,
    const float* __restrict__ wv, const float* __restrict__ wo,
    bf16* __restrict__ wqb, bf16* __restrict__ wkb,
    bf16* __restrict__ wvb, bf16* __restrict__ wob)
{
    int base = (blockIdx.x * 256 + threadIdx.x) * 8;   // 128*256*8 = 4*65536
    int mat = base >> 16, off = base & 65535;
    const float* s = (mat == 0) ? wq : (mat == 1) ? wk : (mat == 2) ? wv : wo;
    bf16* d = (mat == 0) ? wqb : (mat == 1) ? wkb : (mat == 2) ? wvb : wob;
    int doff = (mat == 3) ? off : (off ^ (((off >> 8) & 7) << 3));
    bf16 tmp[8];
    #pragma unroll
    for (int j = 0; j < 8; ++j) tmp[j] = f2b(s[off + j]);
    *(s8v*)&d[doff] = *(const s8v*)tmp;
}

// ---------------------------------------------------------------------------
// qkvprep v5 (unchanged): weights staged via async global_load_lds
// (dual-stream dbuf); packed bf16x4 outputs; V written FRAG-PACKED
// [b][m16][c][16] so flash V loads are 64-lane contiguous 1KB.
// ---------------------------------------------------------------------------
__global__ __launch_bounds__(512, 4) void qkvprep_kernel(
    const float* __restrict__ x,
    const bf16* __restrict__ Wq, const bf16* __restrict__ Wk,
    const bf16* __restrict__ Wv,
    const float* __restrict__ bq, const float* __restrict__ bk,
    const float* __restrict__ bv,
    bf16* __restrict__ qTt, bf16* __restrict__ kTt, bf16* __restrict__ Vt)
{
    __shared__ bf16 xs[64][260];        // [n local][c], 33,280 B
    __shared__ bf16 wbuf[2][2][4096];   // [stream(ch)][parity][16x256] 16,384 B

    const int tile = blockIdx.x;
    const int flat0 = tile * 64;
    const int phase = blockIdx.y;
    const int b = flat0 >> 11, nn = flat0 & 2047;
    const int tid = threadIdx.x;
    const int w = tid >> 6, lane = tid & 63;
    const int l15 = lane & 15, quad = lane >> 4;
    const int ng = w & 3;          // n-group (rows ng*16..+15)
    const int ch = w >> 2;         // c-half stream (0/1)
    const float* xb = x + (size_t)b * CCH * NSEQ;

    bf16* qt = qTt + (size_t)tile * 16384;
    bf16* kt = kTt + (size_t)tile * 16384;
    bf16* Vtb = Vt + (size_t)b * CCH * NSEQ;

    // my stream's chunk base pointer for step j (weights pre-swizzled)
    auto chunk_ptr = [&](int j) -> const bf16* {
        if (phase == 0)
            return (j < 8) ? Wq + (size_t)(ch * 8 + j) * 4096
                           : Wk + (size_t)(ch * 4 + (j - 8)) * 4096;
        else
            return (j < 8) ? Wv + (size_t)(ch * 8 + j) * 4096
                           : Wk + (size_t)(8 + ch * 4 + (j - 8)) * 4096;
    };
    // wave w DMAs 2 of the 8 1KB segments of its stream's next chunk
    auto stage = [&](int j, int par) {
        const bf16* src = chunk_ptr(j);
        bf16* dst = &wbuf[ch][par][0];
        int seg = (w & 3) * 2;
        gload_lds16(src + (seg + 0) * 512 + lane * 8, dst + (seg + 0) * 512);
        gload_lds16(src + (seg + 1) * 512 + lane * 8, dst + (seg + 1) * 512);
    };

    // prologue: stage chunk 0 (async) + x tile transpose, one barrier
    stage(0, 0);
    #pragma unroll
    for (int i = 0; i < 8; ++i) {
        int f4i = i * 512 + tid;
        int c = f4i >> 4, nq = f4i & 15;
        float4 v4 = *(const float4*)&xb[(size_t)c * NSEQ + nn + nq * 4];
        xs[nq * 4 + 0][c] = f2b(v4.x);
        xs[nq * 4 + 1][c] = f2b(v4.y);
        xs[nq * 4 + 2][c] = f2b(v4.z);
        xs[nq * 4 + 3][c] = f2b(v4.w);
    }
    __syncthreads();

    s8v xf[8];
    #pragma unroll
    for (int t = 0; t < 8; ++t)
        xf[t] = *(const s8v*)&xs[ng * 16 + l15][t * 32 + quad * 8];

    int par = 0;
    #pragma unroll
    for (int j = 0; j < 12; ++j) {
        if (j < 11) stage(j + 1, par ^ 1);

        // wf frags from LDS (XOR-deswizzle): W[cs*16+l15][t*32+quad*8 ..+8]
        const char* wb = (const char*)&wbuf[ch][par][0];
        s8v wf[8];
        #pragma unroll
        for (int t = 0; t < 8; ++t)
            wf[t] = *(const s8v*)(wb + l15 * 512 +
                                  ((t * 64 + quad * 16) ^ ((l15 & 7) << 4)));

        if (phase == 0 || j >= 8) {
            // q/k: D[c_local][n] = W*x^T. A=wf -> out row(reg)=c, col(l15)=n.
            f4v a0 = {}, a1 = {};
            #pragma unroll
            for (int t = 0; t < 4; ++t) {
                a0 = MFMA16(wf[t], xf[t], a0);
                a1 = MFMA16(wf[t + 4], xf[t + 4], a1);
            }
            const bool isq = (phase == 0) && (j < 8);
            const int cs = (phase == 0)
                ? (j < 8 ? ch * 8 + j : ch * 4 + (j - 8))
                : (8 + ch * 4 + (j - 8));
            const float* bm = isq ? bq : bk;
            bf16* ot = isq ? qt : kt;
            const float sc = isq ? 0.0625f : 1.0f;
            float4 bb4 = *(const float4*)&bm[cs * 16 + quad * 4];
            float bbr[4] = { bb4.x, bb4.y, bb4.z, bb4.w };
            bf16x4 pk;
            #pragma unroll
            for (int r = 0; r < 4; ++r)
                pk.v[r] = f2b((a0[r] + a1[r] + bbr[r]) * sc);
            // c = cs*16 + quad*4 + r (consecutive): T64 addr contiguous
            int nl = ng * 16 + l15;
            *(bf16x4*)&ot[(cs * 2 + (quad >> 1)) * 512 + nl * 8 + (quad & 1) * 4] = pk;
        } else {
            // v: D[n][c]. A=xf -> out row(reg)=n, col(l15)=c. Frag-packed store.
            f4v a0 = {}, a1 = {};
            #pragma unroll
            for (int t = 0; t < 4; ++t) {
                a0 = MFMA16(xf[t], wf[t], a0);
                a1 = MFMA16(xf[t + 4], wf[t + 4], a1);
            }
            const int cs = ch * 8 + j;
            int c = cs * 16 + l15;
            float bb = bv[c];
            bf16x4 pk;
            #pragma unroll
            for (int r = 0; r < 4; ++r)
                pk.v[r] = f2b(a0[r] + a1[r] + bb);
            const int m16 = (nn >> 4) + ng;
            size_t e0 = ((size_t)m16 * 256 + c) * 16 + (quad >> 1) * 8 + (quad & 1) * 4;
            *(bf16x4*)&Vtb[e0] = pk;
        }
        __syncthreads();   // chunk j reads done; chunk j+1 DMA drained
        par ^= 1;
    }
}

// ---------------------------------------------------------------------------
// flash v12: R6 base (best: 49.0us; staged Kc + swapped QK) with TWO m-tiles
// per barrier pair (T3 amortization). R7's K-direct was -2.3us: K loads on
// the QK critical path can't hide at 2 waves/SIMD -> keep async-DMA staging.
// Outer loop (8 iters): QK(2t)->Ps[0], QK(2t+1)->Ps[1], barrier B,
// stage Kc[0/1]<-tiles 2t+2/2t+3 (spans PV), PV(0)+PV(1), barrier C.
// Barriers per m-tile: 2 -> 1; MFMA per barrier doubles.
// LDS 50.7KB -> 2 blocks/CU (L2-safe regime preserved).
// ---------------------------------------------------------------------------
__global__ __launch_bounds__(256, 2) void flash_kernel(
    const bf16* __restrict__ qTt, const bf16* __restrict__ kTt,
    const bf16* __restrict__ Vt, bf16* __restrict__ Opart,
    float* __restrict__ lpart)
{
    __shared__ bf16 Kc[2][16384];   // two K m-tiles  65,536/2=32,768 B
    __shared__ bf16 Ps[2][64][68];  // [u][n][m]  17,408 B (34 dw, gcd 2)
    __shared__ float l_s[2][64];

    const int b = blockIdx.x, nt = blockIdx.y, ms = blockIdx.z;
    const int tid = threadIdx.x;
    const int W = tid >> 6, lane = tid & 63;
    const int l31 = lane & 31, h = lane >> 5;
    const int ng = W >> 1, mg = W & 1;
    const int mb = ms * 16;          // m-tile base (tiles of 64)
    const bf16* Vtb = Vt + (size_t)b * CCH * NSEQ;

    // Q A-frags (persistent): rows ng*32+l31 of tile (b*32+nt), coalesced
    s8v qf[16];
    {
        const bf16* qt = qTt + (size_t)(b * 32 + nt) * 16384;
        #pragma unroll
        for (int t = 0; t < 16; ++t)
            qf[t] = *(const s8v*)&qt[(t * 2 + h) * 512 + (ng * 32 + l31) * 8];
    }
    // frag-packed V: lane reads elems ((m16*256 + W*64+cr*32+l31)*16 + h*8)
    const bf16* vbase = Vtb + (size_t)(W * 64 + l31) * 16 + h * 8;

    f16v O[2][2] = {};       // [cr][g2]: D[c][n] 32x32 tiles
    float lsum = 0.f;

    auto stageK = [&](int a, int buf) {
        const bf16* kt = kTt + (size_t)(b * 32 + a) * 16384;
        #pragma unroll
        for (int i = 0; i < 8; ++i) {
            int ch = W * 8 + i;
            gload_lds16(kt + ch * 512 + lane * 8, &Kc[buf][ch * 512]);
        }
    };

    // prologue: async-stage K tiles mb, mb+1; barrier (drains vmcnt)
    stageK(mb + 0, 0);
    stageK(mb + 1, 1);
    __syncthreads();

    for (int t8 = 0; t8 < 8; ++t8) {
        s8v vf[2][2][4];     // [u][cr][ks]
        // ---- u = 0,1: QK + V-prefetch + exp -> Ps[u] ----
        #pragma unroll
        for (int u = 0; u < 2; ++u) {
            const int mt = mb + t8 * 2 + u;
            f16v S0 = {}, S1 = {};
            __builtin_amdgcn_s_setprio(1);
            #pragma unroll
            for (int t = 0; t < 8; ++t) {
                s8v kf0 = *(const s8v*)&Kc[u][(t * 2 + h) * 512 + (mg * 32 + l31) * 8];
                s8v kf1 = *(const s8v*)&Kc[u][((t + 8) * 2 + h) * 512 + (mg * 32 + l31) * 8];
                S0 = MFMA32(kf0, qf[t], S0);
                S1 = MFMA32(kf1, qf[t + 8], S1);
            }
            __builtin_amdgcn_s_setprio(0);
            // prefetch V frags (contiguous 1KB/inst; drained by barrier B)
            #pragma unroll
            for (int ks = 0; ks < 4; ++ks)
                #pragma unroll
                for (int cr = 0; cr < 2; ++cr)
                    vf[u][cr][ks] = *(const s8v*)(vbase
                        + (size_t)(mt * 4 + ks) * 4096 + cr * 512);
            // exp + PACKED Ps publish (4 x b64) + scalar l
            #pragma unroll
            for (int q = 0; q < 4; ++q) {
                bf16x4 pk;
                #pragma unroll
                for (int r = 0; r < 4; ++r) {
                    float e = __expf(fminf(S0[q * 4 + r] + S1[q * 4 + r], 60.f));
                    lsum += e;
                    pk.v[r] = f2b(e);
                }
                *(bf16x4*)&Ps[u][ng * 32 + l31][mg * 32 + q * 8 + h * 4] = pk;
            }
        }
        __syncthreads();   // (B) Ps[0],Ps[1] ready; Kc reads + V loads done

        // async-stage next two K tiles (spans PV; drained at barrier C)
        if (t8 < 7) {
            stageK(mb + t8 * 2 + 2, 0);
            stageK(mb + t8 * 2 + 3, 1);
        }
        // ---- PV for both m-tiles ----
        __builtin_amdgcn_s_setprio(1);
        #pragma unroll
        for (int u = 0; u < 2; ++u)
            #pragma unroll
            for (int ks = 0; ks < 4; ++ks) {
                s8v pf0 = *(const s8v*)&Ps[u][l31][ks * 16 + h * 8];
                s8v pf1 = *(const s8v*)&Ps[u][32 + l31][ks * 16 + h * 8];
                O[0][0] = MFMA32(vf[u][0][ks], pf0, O[0][0]);
                O[0][1] = MFMA32(vf[u][0][ks], pf1, O[0][1]);
                O[1][0] = MFMA32(vf[u][1][ks], pf0, O[1][0]);
                O[1][1] = MFMA32(vf[u][1][ks], pf1, O[1][1]);
            }
        __builtin_amdgcn_s_setprio(0);
        __syncthreads();   // (C) PV reads done; next Kc DMA drained
    }

    // l: lane holds sum over its 16 m; combine h pair, then mg pair
    {
        float s = lsum + __shfl_xor(lsum, 32);
        if (h == 0) l_s[mg][ng * 32 + l31] = s;
    }
    __syncthreads();
    const size_t pb = (size_t)(b * 32 + nt) * 2 + ms;
    if (tid < 64) lpart[pb * 64 + tid] = l_s[0][tid] + l_s[1][tid];

    // O partials -> ws, layout [n][c] bf16 (contiguous 32KB per pb)
    bf16* Ob = Opart + pb * 16384;
    #pragma unroll
    for (int cr = 0; cr < 2; ++cr)
        #pragma unroll
        for (int g2 = 0; g2 < 2; ++g2) {
            int n = g2 * 32 + l31;
            #pragma unroll
            for (int q2 = 0; q2 < 4; ++q2) {
                bf16x4 pk;
                #pragma unroll
                for (int j = 0; j < 4; ++j) pk.v[j] = f2b(O[cr][g2][q2 * 4 + j]);
                int c = W * 64 + cr * 32 + q2 * 8 + 4 * h;
                *(bf16x4*)&Ob[(size_t)n * 256 + c] = pk;
            }
        }
}

// ---------------------------------------------------------------------------
// outproj v5 (unchanged): 512-thread blocks, 16 waves/CU; Wo pre-cast bf16.
// out[c][n] = x[c][n] + bo[c] + sum_i Wo[c][i]*avs[n][i], fp32.
// ---------------------------------------------------------------------------
__global__ __launch_bounds__(512, 4) void outproj_kernel(
    const bf16* __restrict__ Opart, const float* __restrict__ lpart,
    const bf16* __restrict__ Wob, const float* __restrict__ bo,
    const float* __restrict__ x, float* __restrict__ out)
{
    __shared__ bf16 avs[64][260];
    __shared__ float ils[64];

    const int bx = blockIdx.x;
    const int flat0 = bx * 64;
    const int c0 = blockIdx.y * 128;
    const int tid = threadIdx.x;
    const int w = tid >> 6, lane = tid & 63;
    const int l15 = lane & 15, quad = lane >> 4;

    if (tid < 64)
        ils[tid] = 1.f / (lpart[(size_t)(bx * 2) * 64 + tid]
                        + lpart[(size_t)(bx * 2 + 1) * 64 + tid]);
    __syncthreads();

    const bf16x4* O0 = (const bf16x4*)(Opart + (size_t)(bx * 2) * 16384);
    const bf16x4* O1 = O0 + 4096;
    #pragma unroll
    for (int i = 0; i < 8; ++i) {
        int u = i * 512 + tid;
        int n = u >> 6;
        bf16x4 a = O0[u], bb = O1[u];
        float il = ils[n];
        bf16x4 o;
        #pragma unroll
        for (int t = 0; t < 4; ++t)
            o.v[t] = f2b((b2f(a.v[t]) + b2f(bb.v[t])) * il);
        *(bf16x4*)&avs[n][(u & 63) * 4] = o;
    }
    __syncthreads();

    const int bidx = flat0 >> 11, nn = flat0 & 2047;
    const size_t base = (size_t)bidx * CCH * NSEQ;
    const int cg = c0 + w * 16;     // each of 8 waves owns one 16-c slice

    s8v af[8];
    #pragma unroll
    for (int t = 0; t < 8; ++t)
        af[t] = *(const s8v*)&Wob[(size_t)(cg + l15) * CCH + t * 32 + quad * 8];

    f4v O[4] = {};
    #pragma unroll
    for (int nt = 0; nt < 4; ++nt)
        #pragma unroll
        for (int t = 0; t < 8; ++t) {
            s8v br = *(const s8v*)&avs[nt * 16 + l15][t * 32 + quad * 8];
            O[nt] = MFMA16(af[t], br, O[nt]);
        }
    #pragma unroll
    for (int r = 0; r < 4; ++r) {
        int c = cg + quad * 4 + r;
        float bb = bo[c];
        #pragma unroll
        for (int nt = 0; nt < 4; ++nt) {
            size_t idx = base + (size_t)c * NSEQ + nn + nt * 16 + l15;
            out[idx] = O[nt][r] + bb + x[idx];
        }
    }
}

// ---------------------------------------------------------------------------
extern "C" void kernel_launch(void* const* d_in, const int* in_sizes, int n_in,
                              void* d_out, int out_size, void* d_ws, size_t ws_size,
                              hipStream_t stream) {
    (void)in_sizes; (void)n_in; (void)out_size; (void)ws_size;
    const float* x  = (const float*)d_in[0];
    const float* wq = (const float*)d_in[1];
    const float* bq = (const float*)d_in[2];
    const float* wk = (const float*)d_in[3];
    const float* bk = (const float*)d_in[4];
    const float* wv = (const float*)d_in[5];
    const float* bv = (const float*)d_in[6];
    const float* wo = (const float*)d_in[7];
    const float* bo = (const float*)d_in[8];
    float* out = (float*)d_out;

    const size_t T = (size_t)BATCH * CCH * NSEQ;   // 4,194,304
    bf16* qTt  = (bf16*)d_ws;          // T64 tile-major [256 tiles][32][64][8]
    bf16* kTt  = qTt + T;
    bf16* Vt   = kTt + T;              // frag-packed [b][m16][c][16]
    bf16* wqb  = Vt + T;               // pre-swizzled bf16 weights
    bf16* wkb  = wqb + 65536;
    bf16* wvb  = wkb + 65536;
    bf16* wob  = wvb + 65536;          // plain bf16 Wo
    float* lpart = (float*)(wob + 65536);        // 512 * 64 f32
    bf16* Opart  = (bf16*)(lpart + 32768);       // 512 * 16384 bf16
    // total ws: 25.2 + 0.5 + 0.13 + 16.8 MB ~ 42.6 MB

    prepw_kernel<<<128, 256, 0, stream>>>(wq, wk, wv, wo, wqb, wkb, wvb, wob);
    qkvprep_kernel<<<dim3(256, 2), 512, 0, stream>>>(
        x, wqb, wkb, wvb, bq, bk, bv, qTt, kTt, Vt);
    flash_kernel<<<dim3(8, 32, 2), 256, 0, stream>>>(qTt, kTt, Vt, Opart, lpart);
    outproj_kernel<<<dim3(256, 2), 512, 0, stream>>>(Opart, lpart, wob, bo, x, out);
}

// Round 9
// 154.718 us; speedup vs baseline: 1.0845x; 1.0845x over previous
//
#include <hip/hip_runtime.h>
#include <hip/hip_bf16.h>

#define CCH 256
#define NSEQ 2048
#define BATCH 8

typedef __hip_bfloat16 bf16;
typedef short s8v __attribute__((ext_vector_type(8)));    // 8 bf16 (A/B frag)
typedef float f4v __attribute__((ext_vector_type(4)));    // 16x16 C/D frag
typedef float f16v __attribute__((ext_vector_type(16)));  // 32x32 C/D frag

struct __align__(8) bf16x4 { bf16 v[4]; };

__device__ __forceinline__ float b2f(bf16 h) { return __bfloat162float(h); }
__device__ __forceinline__ bf16 f2b(float f) { return __float2bfloat16(f); }

#define MFMA16(a, b, c) __builtin_amdgcn_mfma_f32_16x16x32_bf16((a), (b), (c), 0, 0, 0)
#define MFMA32(a, b, c) __builtin_amdgcn_mfma_f32_32x32x16_bf16((a), (b), (c), 0, 0, 0)

// async global->LDS 16B per lane: lds dest = uniform base + lane*16
__device__ __forceinline__ void gload_lds16(const bf16* g, bf16* l) {
    __builtin_amdgcn_global_load_lds(
        (const __attribute__((address_space(1))) unsigned int*)(g),
        (__attribute__((address_space(3))) unsigned int*)(l), 16, 0, 0);
}

// ---------------------------------------------------------------------------
// prepw: cast Wq,Wk,Wv,Wo fp32 -> bf16 once. Wq/Wk/Wv PRE-SWIZZLED
// (elem ^= (row&7)<<3) for qkvprep's LDS-DMA + swizzled ds_read_b128.
// Wo plain bf16 (outproj reads per-wave frags directly from global).
// ---------------------------------------------------------------------------
__global__ __launch_bounds__(256) void prepw_kernel(
    const float* __restrict__ wq, const float* __restrict__ wk,
    const float* __restrict__ wv, const float* __restrict__ wo,
    bf16* __restrict__ wqb, bf16* __restrict__ wkb,
    bf16* __restrict__ wvb, bf16* __restrict__ wob)
{
    int base = (blockIdx.x * 256 + threadIdx.x) * 8;   // 128*256*8 = 4*65536
    int mat = base >> 16, off = base & 65535;
    const float* s = (mat == 0) ? wq : (mat == 1) ? wk : (mat == 2) ? wv : wo;
    bf16* d = (mat == 0) ? wqb : (mat == 1) ? wkb : (mat == 2) ? wvb : wob;
    int doff = (mat == 3) ? off : (off ^ (((off >> 8) & 7) << 3));
    bf16 tmp[8];
    #pragma unroll
    for (int j = 0; j < 8; ++j) tmp[j] = f2b(s[off + j]);
    *(s8v*)&d[doff] = *(const s8v*)tmp;
}

// ---------------------------------------------------------------------------
// qkvprep v5 (unchanged): weights staged via async global_load_lds
// (dual-stream dbuf); packed bf16x4 outputs; V written FRAG-PACKED
// [b][m16][c][16] so flash V loads are 64-lane contiguous 1KB.
// ---------------------------------------------------------------------------
__global__ __launch_bounds__(512, 4) void qkvprep_kernel(
    const float* __restrict__ x,
    const bf16* __restrict__ Wq, const bf16* __restrict__ Wk,
    const bf16* __restrict__ Wv,
    const float* __restrict__ bq, const float* __restrict__ bk,
    const float* __restrict__ bv,
    bf16* __restrict__ qTt, bf16* __restrict__ kTt, bf16* __restrict__ Vt)
{
    __shared__ bf16 xs[64][260];        // [n local][c], 33,280 B
    __shared__ bf16 wbuf[2][2][4096];   // [stream(ch)][parity][16x256] 16,384 B

    const int tile = blockIdx.x;
    const int flat0 = tile * 64;
    const int phase = blockIdx.y;
    const int b = flat0 >> 11, nn = flat0 & 2047;
    const int tid = threadIdx.x;
    const int w = tid >> 6, lane = tid & 63;
    const int l15 = lane & 15, quad = lane >> 4;
    const int ng = w & 3;          // n-group (rows ng*16..+15)
    const int ch = w >> 2;         // c-half stream (0/1)
    const float* xb = x + (size_t)b * CCH * NSEQ;

    bf16* qt = qTt + (size_t)tile * 16384;
    bf16* kt = kTt + (size_t)tile * 16384;
    bf16* Vtb = Vt + (size_t)b * CCH * NSEQ;

    // my stream's chunk base pointer for step j (weights pre-swizzled)
    auto chunk_ptr = [&](int j) -> const bf16* {
        if (phase == 0)
            return (j < 8) ? Wq + (size_t)(ch * 8 + j) * 4096
                           : Wk + (size_t)(ch * 4 + (j - 8)) * 4096;
        else
            return (j < 8) ? Wv + (size_t)(ch * 8 + j) * 4096
                           : Wk + (size_t)(8 + ch * 4 + (j - 8)) * 4096;
    };
    // wave w DMAs 2 of the 8 1KB segments of its stream's next chunk
    auto stage = [&](int j, int par) {
        const bf16* src = chunk_ptr(j);
        bf16* dst = &wbuf[ch][par][0];
        int seg = (w & 3) * 2;
        gload_lds16(src + (seg + 0) * 512 + lane * 8, dst + (seg + 0) * 512);
        gload_lds16(src + (seg + 1) * 512 + lane * 8, dst + (seg + 1) * 512);
    };

    // prologue: stage chunk 0 (async) + x tile transpose, one barrier
    stage(0, 0);
    #pragma unroll
    for (int i = 0; i < 8; ++i) {
        int f4i = i * 512 + tid;
        int c = f4i >> 4, nq = f4i & 15;
        float4 v4 = *(const float4*)&xb[(size_t)c * NSEQ + nn + nq * 4];
        xs[nq * 4 + 0][c] = f2b(v4.x);
        xs[nq * 4 + 1][c] = f2b(v4.y);
        xs[nq * 4 + 2][c] = f2b(v4.z);
        xs[nq * 4 + 3][c] = f2b(v4.w);
    }
    __syncthreads();

    s8v xf[8];
    #pragma unroll
    for (int t = 0; t < 8; ++t)
        xf[t] = *(const s8v*)&xs[ng * 16 + l15][t * 32 + quad * 8];

    int par = 0;
    #pragma unroll
    for (int j = 0; j < 12; ++j) {
        if (j < 11) stage(j + 1, par ^ 1);

        // wf frags from LDS (XOR-deswizzle): W[cs*16+l15][t*32+quad*8 ..+8]
        const char* wb = (const char*)&wbuf[ch][par][0];
        s8v wf[8];
        #pragma unroll
        for (int t = 0; t < 8; ++t)
            wf[t] = *(const s8v*)(wb + l15 * 512 +
                                  ((t * 64 + quad * 16) ^ ((l15 & 7) << 4)));

        if (phase == 0 || j >= 8) {
            // q/k: D[c_local][n] = W*x^T. A=wf -> out row(reg)=c, col(l15)=n.
            f4v a0 = {}, a1 = {};
            #pragma unroll
            for (int t = 0; t < 4; ++t) {
                a0 = MFMA16(wf[t], xf[t], a0);
                a1 = MFMA16(wf[t + 4], xf[t + 4], a1);
            }
            const bool isq = (phase == 0) && (j < 8);
            const int cs = (phase == 0)
                ? (j < 8 ? ch * 8 + j : ch * 4 + (j - 8))
                : (8 + ch * 4 + (j - 8));
            const float* bm = isq ? bq : bk;
            bf16* ot = isq ? qt : kt;
            const float sc = isq ? 0.0625f : 1.0f;
            float4 bb4 = *(const float4*)&bm[cs * 16 + quad * 4];
            float bbr[4] = { bb4.x, bb4.y, bb4.z, bb4.w };
            bf16x4 pk;
            #pragma unroll
            for (int r = 0; r < 4; ++r)
                pk.v[r] = f2b((a0[r] + a1[r] + bbr[r]) * sc);
            // c = cs*16 + quad*4 + r (consecutive): T64 addr contiguous
            int nl = ng * 16 + l15;
            *(bf16x4*)&ot[(cs * 2 + (quad >> 1)) * 512 + nl * 8 + (quad & 1) * 4] = pk;
        } else {
            // v: D[n][c]. A=xf -> out row(reg)=n, col(l15)=c. Frag-packed store.
            f4v a0 = {}, a1 = {};
            #pragma unroll
            for (int t = 0; t < 4; ++t) {
                a0 = MFMA16(xf[t], wf[t], a0);
                a1 = MFMA16(xf[t + 4], wf[t + 4], a1);
            }
            const int cs = ch * 8 + j;
            int c = cs * 16 + l15;
            float bb = bv[c];
            bf16x4 pk;
            #pragma unroll
            for (int r = 0; r < 4; ++r)
                pk.v[r] = f2b(a0[r] + a1[r] + bb);
            const int m16 = (nn >> 4) + ng;
            size_t e0 = ((size_t)m16 * 256 + c) * 16 + (quad >> 1) * 8 + (quad & 1) * 4;
            *(bf16x4*)&Vtb[e0] = pk;
        }
        __syncthreads();   // chunk j reads done; chunk j+1 DMA drained
        par ^= 1;
    }
}

// ---------------------------------------------------------------------------
// flash v13 = R6 schedule EXACTLY (best measured: 49.0us) with ONE delta:
// V-frag prefetch hoisted to the TOP of the iteration (before QK).
// Mechanism: barrier B's compiler-forced vmcnt(0) drain waited on the V
// loads, which R6 issued after QK (only exp ~100cyc of cover). At the top
// they get the full QK span (~600+cyc) to land -> drain cost ~0.
// (R8's 2-tile batching was an LDS arithmetic bust: Kc[2] = 81.5KB -> 1
// block/CU, occ 10%. Reverted.)
// Grid (8,32,2) = 512 blocks = 2 blocks/CU (L2-safe). LDS 42KB.
// ---------------------------------------------------------------------------
__global__ __launch_bounds__(256, 2) void flash_kernel(
    const bf16* __restrict__ qTt, const bf16* __restrict__ kTt,
    const bf16* __restrict__ Vt, bf16* __restrict__ Opart,
    float* __restrict__ lpart)
{
    __shared__ bf16 Kc[16384];      // [cblk32][m64][8]  32,768 B
    __shared__ bf16 Ps[64][68];     // [n][m]  8,704 B (34 dw stride, gcd 2)
    __shared__ float l_s[2][64];

    const int b = blockIdx.x, nt = blockIdx.y, ms = blockIdx.z;
    const int tid = threadIdx.x;
    const int W = tid >> 6, lane = tid & 63;
    const int l31 = lane & 31, h = lane >> 5;
    const int ng = W >> 1, mg = W & 1;
    const int mb = ms * 16;          // m-tile base (tiles of 64)
    const bf16* Vtb = Vt + (size_t)b * CCH * NSEQ;

    // Q A-frags (persistent): rows ng*32+l31 of tile (b*32+nt), coalesced
    s8v qf[16];
    {
        const bf16* qt = qTt + (size_t)(b * 32 + nt) * 16384;
        #pragma unroll
        for (int t = 0; t < 16; ++t)
            qf[t] = *(const s8v*)&qt[(t * 2 + h) * 512 + (ng * 32 + l31) * 8];
    }
    // frag-packed V: lane reads elems ((m16*256 + W*64+cr*32+l31)*16 + h*8)
    const bf16* vbase = Vtb + (size_t)(W * 64 + l31) * 16 + h * 8;

    f16v O[2][2] = {};       // [cr][g2]: D[c][n] 32x32 tiles
    float lsum = 0.f;

    auto stageK = [&](int a) {
        const bf16* kt = kTt + (size_t)(b * 32 + a) * 16384;
        #pragma unroll
        for (int i = 0; i < 8; ++i) {
            int ch = W * 8 + i;
            gload_lds16(kt + ch * 512 + lane * 8, &Kc[ch * 512]);
        }
    };

    // prologue: async-stage K tile mb, then barrier (drains vmcnt)
    stageK(mb);
    __syncthreads();

    for (int mt = 0; mt < 16; ++mt) {
        // V-frag prefetch FIRST: full QK span covers the L2 latency before
        // barrier B's vmcnt(0) drain (contiguous 1KB/inst)
        s8v vf[2][4];
        #pragma unroll
        for (int ks = 0; ks < 4; ++ks)
            #pragma unroll
            for (int cr = 0; cr < 2; ++cr)
                vf[cr][ks] = *(const s8v*)(vbase
                    + (size_t)((mb + mt) * 4 + ks) * 4096 + cr * 512);

        // QK swapped: S^T = MFMA(K,Q); two 8-deep c-half chains
        f16v S0 = {}, S1 = {};
        __builtin_amdgcn_s_setprio(1);
        #pragma unroll
        for (int t = 0; t < 8; ++t) {
            s8v kf0 = *(const s8v*)&Kc[(t * 2 + h) * 512 + (mg * 32 + l31) * 8];
            s8v kf1 = *(const s8v*)&Kc[((t + 8) * 2 + h) * 512 + (mg * 32 + l31) * 8];
            S0 = MFMA32(kf0, qf[t], S0);
            S1 = MFMA32(kf1, qf[t + 8], S1);
        }
        __builtin_amdgcn_s_setprio(0);
        // exp + PACKED Ps publish (4 x b64) + scalar l
        #pragma unroll
        for (int q = 0; q < 4; ++q) {
            bf16x4 pk;
            #pragma unroll
            for (int r = 0; r < 4; ++r) {
                float e = __expf(fminf(S0[q * 4 + r] + S1[q * 4 + r], 60.f));
                lsum += e;
                pk.v[r] = f2b(e);
            }
            *(bf16x4*)&Ps[ng * 32 + l31][mg * 32 + q * 8 + h * 4] = pk;
        }
        __syncthreads();   // (B) Ps ready; all QK reads of Kc done

        // async-stage next K tile (spans PV; drained at barrier C)
        if (mt < 15) stageK(mb + mt + 1);

        // PV: O[c][n] += V[c][m] * P^T[m][n]
        __builtin_amdgcn_s_setprio(1);
        #pragma unroll
        for (int ks = 0; ks < 4; ++ks) {
            s8v pf0 = *(const s8v*)&Ps[l31][ks * 16 + h * 8];
            s8v pf1 = *(const s8v*)&Ps[32 + l31][ks * 16 + h * 8];
            O[0][0] = MFMA32(vf[0][ks], pf0, O[0][0]);
            O[0][1] = MFMA32(vf[0][ks], pf1, O[0][1]);
            O[1][0] = MFMA32(vf[1][ks], pf0, O[1][0]);
            O[1][1] = MFMA32(vf[1][ks], pf1, O[1][1]);
        }
        __builtin_amdgcn_s_setprio(0);
        __syncthreads();   // (C) PV reads done; K(mt+1) drained
    }

    // l: lane holds sum over its 16 m; combine h pair, then mg pair
    {
        float s = lsum + __shfl_xor(lsum, 32);
        if (h == 0) l_s[mg][ng * 32 + l31] = s;
    }
    __syncthreads();
    const size_t pb = (size_t)(b * 32 + nt) * 2 + ms;
    if (tid < 64) lpart[pb * 64 + tid] = l_s[0][tid] + l_s[1][tid];

    // O partials -> ws, layout [n][c] bf16 (contiguous 32KB per pb)
    bf16* Ob = Opart + pb * 16384;
    #pragma unroll
    for (int cr = 0; cr < 2; ++cr)
        #pragma unroll
        for (int g2 = 0; g2 < 2; ++g2) {
            int n = g2 * 32 + l31;
            #pragma unroll
            for (int q2 = 0; q2 < 4; ++q2) {
                bf16x4 pk;
                #pragma unroll
                for (int j = 0; j < 4; ++j) pk.v[j] = f2b(O[cr][g2][q2 * 4 + j]);
                int c = W * 64 + cr * 32 + q2 * 8 + 4 * h;
                *(bf16x4*)&Ob[(size_t)n * 256 + c] = pk;
            }
        }
}

// ---------------------------------------------------------------------------
// outproj v5 (unchanged): 512-thread blocks, 16 waves/CU; Wo pre-cast bf16.
// out[c][n] = x[c][n] + bo[c] + sum_i Wo[c][i]*avs[n][i], fp32.
// ---------------------------------------------------------------------------
__global__ __launch_bounds__(512, 4) void outproj_kernel(
    const bf16* __restrict__ Opart, const float* __restrict__ lpart,
    const bf16* __restrict__ Wob, const float* __restrict__ bo,
    const float* __restrict__ x, float* __restrict__ out)
{
    __shared__ bf16 avs[64][260];
    __shared__ float ils[64];

    const int bx = blockIdx.x;
    const int flat0 = bx * 64;
    const int c0 = blockIdx.y * 128;
    const int tid = threadIdx.x;
    const int w = tid >> 6, lane = tid & 63;
    const int l15 = lane & 15, quad = lane >> 4;

    if (tid < 64)
        ils[tid] = 1.f / (lpart[(size_t)(bx * 2) * 64 + tid]
                        + lpart[(size_t)(bx * 2 + 1) * 64 + tid]);
    __syncthreads();

    const bf16x4* O0 = (const bf16x4*)(Opart + (size_t)(bx * 2) * 16384);
    const bf16x4* O1 = O0 + 4096;
    #pragma unroll
    for (int i = 0; i < 8; ++i) {
        int u = i * 512 + tid;
        int n = u >> 6;
        bf16x4 a = O0[u], bb = O1[u];
        float il = ils[n];
        bf16x4 o;
        #pragma unroll
        for (int t = 0; t < 4; ++t)
            o.v[t] = f2b((b2f(a.v[t]) + b2f(bb.v[t])) * il);
        *(bf16x4*)&avs[n][(u & 63) * 4] = o;
    }
    __syncthreads();

    const int bidx = flat0 >> 11, nn = flat0 & 2047;
    const size_t base = (size_t)bidx * CCH * NSEQ;
    const int cg = c0 + w * 16;     // each of 8 waves owns one 16-c slice

    s8v af[8];
    #pragma unroll
    for (int t = 0; t < 8; ++t)
        af[t] = *(const s8v*)&Wob[(size_t)(cg + l15) * CCH + t * 32 + quad * 8];

    f4v O[4] = {};
    #pragma unroll
    for (int nt = 0; nt < 4; ++nt)
        #pragma unroll
        for (int t = 0; t < 8; ++t) {
            s8v br = *(const s8v*)&avs[nt * 16 + l15][t * 32 + quad * 8];
            O[nt] = MFMA16(af[t], br, O[nt]);
        }
    #pragma unroll
    for (int r = 0; r < 4; ++r) {
        int c = cg + quad * 4 + r;
        float bb = bo[c];
        #pragma unroll
        for (int nt = 0; nt < 4; ++nt) {
            size_t idx = base + (size_t)c * NSEQ + nn + nt * 16 + l15;
            out[idx] = O[nt][r] + bb + x[idx];
        }
    }
}

// ---------------------------------------------------------------------------
extern "C" void kernel_launch(void* const* d_in, const int* in_sizes, int n_in,
                              void* d_out, int out_size, void* d_ws, size_t ws_size,
                              hipStream_t stream) {
    (void)in_sizes; (void)n_in; (void)out_size; (void)ws_size;
    const float* x  = (const float*)d_in[0];
    const float* wq = (const float*)d_in[1];
    const float* bq = (const float*)d_in[2];
    const float* wk = (const float*)d_in[3];
    const float* bk = (const float*)d_in[4];
    const float* wv = (const float*)d_in[5];
    const float* bv = (const float*)d_in[6];
    const float* wo = (const float*)d_in[7];
    const float* bo = (const float*)d_in[8];
    float* out = (float*)d_out;

    const size_t T = (size_t)BATCH * CCH * NSEQ;   // 4,194,304
    bf16* qTt  = (bf16*)d_ws;          // T64 tile-major [256 tiles][32][64][8]
    bf16* kTt  = qTt + T;
    bf16* Vt   = kTt + T;              // frag-packed [b][m16][c][16]
    bf16* wqb  = Vt + T;               // pre-swizzled bf16 weights
    bf16* wkb  = wqb + 65536;
    bf16* wvb  = wkb + 65536;
    bf16* wob  = wvb + 65536;          // plain bf16 Wo
    float* lpart = (float*)(wob + 65536);        // 512 * 64 f32
    bf16* Opart  = (bf16*)(lpart + 32768);       // 512 * 16384 bf16
    // total ws: 25.2 + 0.5 + 0.13 + 16.8 MB ~ 42.6 MB

    prepw_kernel<<<128, 256, 0, stream>>>(wq, wk, wv, wo, wqb, wkb, wvb, wob);
    qkvprep_kernel<<<dim3(256, 2), 512, 0, stream>>>(
        x, wqb, wkb, wvb, bq, bk, bv, qTt, kTt, Vt);
    flash_kernel<<<dim3(8, 32, 2), 256, 0, stream>>>(qTt, kTt, Vt, Opart, lpart);
    outproj_kernel<<<dim3(256, 2), 512, 0, stream>>>(Opart, lpart, wob, bo, x, out);
}